// Round 12
// baseline (41.167 us; speedup 1.0000x reference)
//
#include <hip/hip_runtime.h>

typedef __attribute__((ext_vector_type(4))) float f32x4;
typedef __attribute__((ext_vector_type(2))) long long i64x2;

static constexpr int D = 256;
static constexpr float INV_T = 2.0f;                 // 1 / temperature(0.5)
static constexpr float KEXP2 = 2.8853900817779268f;  // 2*log2(e): exp(2x) = 2^(KEXP2*x)
static constexpr int TTILE = 64;                     // 8192 / 128
static constexpr int NBLK = TTILE * (TTILE + 1) / 2; // 2080 upper-triangle tiles
static constexpr int NPLANE = 2 * TTILE;             // 128 partial planes
static constexpr int LSE_BLOCKS = 32;
// zn fp8 paired-kk fragment layout (per 128-row tile = contiguous 32 KB):
//   byte = ti*32768 + rb*4096 + kkp*1024 + lane*16 + half*8 + e
//   rb=(row>>4)&7, kkp=k>>6, half=(k>>5)&1, lane=((k>>3)&3)*16+(row&15), e=k&7
// Reader: 16B load at (rb*4+kkp)*1024 + lane*16 -> [kk even | kk odd] operands.
// (Layout verified end-to-end in R10/R11: absmax = 0.)

__device__ inline float fexp2(float x) {
#if __has_builtin(__builtin_amdgcn_exp2f)
    return __builtin_amdgcn_exp2f(x);
#else
    return exp2f(x);
#endif
}
// 4 floats -> 4 packed OCP e4m3 bytes (RNE HW instr, bit-identical to MFMA input).
__device__ inline unsigned int cvt4_fp8(float a, float b, float c, float d) {
    int v = __builtin_amdgcn_cvt_pk_fp8_f32(a, b, 0, false);
    v = __builtin_amdgcn_cvt_pk_fp8_f32(c, d, v, true);
    return (unsigned int)v;
}

// Kernel 1 (verified): normalize pair rows to fp8 in the fragment layout;
// diag[i] = -exp(2*selfdot_fp8); pos dot -> block partial. Also resets the
// k_lse completion counter (deterministic per launch; harness doesn't
// re-poison d_ws between replays).
__global__ void k_norm(const float* __restrict__ zi, const float* __restrict__ zj,
                       unsigned char* __restrict__ zn, float* __restrict__ diag,
                       float* __restrict__ pos_partial, unsigned int* __restrict__ counter,
                       int B) {
    __shared__ float red[4];
    const int lane = threadIdx.x & 63;
    const int wv = threadIdx.x >> 6;
    const int i = blockIdx.x * 4 + wv;       // pair index
    if (blockIdx.x == 0 && threadIdx.x == 0) *counter = 0;
    if (i < B) {
        float4 vi = reinterpret_cast<const float4*>(zi + (size_t)i * D)[lane];
        float4 vj = reinterpret_cast<const float4*>(zj + (size_t)i * D)[lane];
        float ssi = vi.x * vi.x + vi.y * vi.y + vi.z * vi.z + vi.w * vi.w;
        float ssj = vj.x * vj.x + vj.y * vj.y + vj.z * vj.z + vj.w * vj.w;
#pragma unroll
        for (int off = 32; off >= 1; off >>= 1) {
            ssi += __shfl_xor(ssi, off, 64);
            ssj += __shfl_xor(ssj, off, 64);
        }
        float rni = rsqrtf(ssi), rnj = rsqrtf(ssj);
        unsigned int pa = cvt4_fp8(vi.x * rni, vi.y * rni, vi.z * rni, vi.w * rni);
        unsigned int pb = cvt4_fp8(vj.x * rnj, vj.y * rnj, vj.z * rnj, vj.w * rnj);
        float fa0 = __builtin_amdgcn_cvt_f32_fp8((int)pa, 0);
        float fa1 = __builtin_amdgcn_cvt_f32_fp8((int)pa, 1);
        float fa2 = __builtin_amdgcn_cvt_f32_fp8((int)pa, 2);
        float fa3 = __builtin_amdgcn_cvt_f32_fp8((int)pa, 3);
        float fb0 = __builtin_amdgcn_cvt_f32_fp8((int)pb, 0);
        float fb1 = __builtin_amdgcn_cvt_f32_fp8((int)pb, 1);
        float fb2 = __builtin_amdgcn_cvt_f32_fp8((int)pb, 2);
        float fb3 = __builtin_amdgcn_cvt_f32_fp8((int)pb, 3);
        float sdi = fa0 * fa0 + fa1 * fa1 + fa2 * fa2 + fa3 * fa3;
        float sdj = fb0 * fb0 + fb1 * fb1 + fb2 * fb2 + fb3 * fb3;
        float pd  = fa0 * fb0 + fa1 * fb1 + fa2 * fb2 + fa3 * fb3;
#pragma unroll
        for (int off = 32; off >= 1; off >>= 1) {
            sdi += __shfl_xor(sdi, off, 64);
            sdj += __shfl_xor(sdj, off, 64);
            pd  += __shfl_xor(pd, off, 64);
        }
        unsigned int qa = __shfl_xor(pa, 1, 64);
        unsigned int qb = __shfl_xor(pb, 1, 64);
        if ((lane & 1) == 0) {
            int m = lane >> 1;   // 0..31 -> k = 8m..8m+7
            size_t base = (size_t)(m >> 3) * 1024 + (size_t)((m & 3) * 16) * 16
                        + (size_t)(((m >> 2) & 1)) * 8;
            size_t offA = (size_t)(i >> 4) * 4096 + base + (size_t)(i & 15) * 16;
            int ib = i + B;
            size_t offB = (size_t)(ib >> 4) * 4096 + base + (size_t)(ib & 15) * 16;
            *reinterpret_cast<unsigned long long*>(zn + offA) =
                ((unsigned long long)qa << 32) | pa;
            *reinterpret_cast<unsigned long long*>(zn + offB) =
                ((unsigned long long)qb << 32) | pb;
        }
        if (lane == 0) {
            diag[i]     = -fexp2(KEXP2 * sdi);
            diag[i + B] = -fexp2(KEXP2 * sdj);
            red[wv] = pd;
        }
    } else if (lane == 0) {
        red[wv] = 0.f;
    }
    __syncthreads();
    if (threadIdx.x == 0)
        pos_partial[blockIdx.x] = 2.0f * INV_T * (red[0] + red[1] + red[2] + red[3]);
}

// Kernel 2: barrier-free, LDS-free upper-triangle tiles (R11 structure,
// verified). Now __launch_bounds__(256,3): the kernel is pure
// {global_load -> MFMA -> exp} with zero syncs, so occupancy converts load
// latency directly into MFMA overlap (R11 pinned 2 blocks/CU; VGPR demand
// ~130 fits the 168 cap for 3).
__global__ __launch_bounds__(256, 3)
void k_main(const unsigned char* __restrict__ zn, float* __restrict__ P, int N) {
    const int tid = threadIdx.x;
    const int lane = tid & 63, wv = tid >> 6;
    const int l15 = lane & 15, lhi = lane >> 4;
    const int wr = wv >> 1, wc = wv & 1;         // wave grid 2 x 2, 64x64 each

    // XCD-aware bijective swizzle (NBLK = 2080 = 8 * 260)
    const int bid = (int)blockIdx.x;
    const int swz = (bid & 7) * (NBLK / 8) + (bid >> 3);
    int ti = 0, rem = swz;
    while (rem >= TTILE - ti) { rem -= TTILE - ti; ++ti; }
    const int tj = ti + rem;

    const i64x2* Ap = reinterpret_cast<const i64x2*>(zn + (size_t)ti * 32768);
    const i64x2* Bp = reinterpret_cast<const i64x2*>(zn + (size_t)tj * 32768);

    f32x4 acc[4][4];
#pragma unroll
    for (int r = 0; r < 4; ++r)
#pragma unroll
        for (int c = 0; c < 4; ++c) acc[r][c] = (f32x4){0.f, 0.f, 0.f, 0.f};

#pragma unroll
    for (int kkp = 0; kkp < 4; ++kkp) {
        i64x2 a_[4], b_[4];
#pragma unroll
        for (int r = 0; r < 4; ++r)
            a_[r] = Ap[((wr * 4 + r) * 4 + kkp) * 64 + lane];
#pragma unroll
        for (int c = 0; c < 4; ++c)
            b_[c] = Bp[((wc * 4 + c) * 4 + kkp) * 64 + lane];
#pragma unroll
        for (int r = 0; r < 4; ++r)
#pragma unroll
            for (int c = 0; c < 4; ++c) {
                acc[r][c] = __builtin_amdgcn_mfma_f32_16x16x32_fp8_fp8(
                    a_[r].x, b_[c].x, acc[r][c], 0, 0, 0);
                acc[r][c] = __builtin_amdgcn_mfma_f32_16x16x32_fp8_fp8(
                    a_[r].y, b_[c].y, acc[r][c], 0, 0, 0);
            }
    }

    // tail: e = exp(2*sim); row-sums -> plane 2*tj+wc; col-sums -> plane
    // 2*ti+wr (off-diag only). row = wr*64+r*16+lhi*4+q, col = wc*64+c*16+l15.
    float cs[4] = {0.f, 0.f, 0.f, 0.f};
#pragma unroll
    for (int r = 0; r < 4; ++r) {
        float rq0 = 0.f, rq1 = 0.f, rq2 = 0.f, rq3 = 0.f;
#pragma unroll
        for (int c = 0; c < 4; ++c) {
            float e0 = fexp2(KEXP2 * acc[r][c][0]);
            float e1 = fexp2(KEXP2 * acc[r][c][1]);
            float e2 = fexp2(KEXP2 * acc[r][c][2]);
            float e3 = fexp2(KEXP2 * acc[r][c][3]);
            rq0 += e0; rq1 += e1; rq2 += e2; rq3 += e3;
            cs[c] += e0 + e1 + e2 + e3;
        }
#pragma unroll
        for (int off = 1; off <= 8; off <<= 1) {
            rq0 += __shfl_xor(rq0, off, 64);
            rq1 += __shfl_xor(rq1, off, 64);
            rq2 += __shfl_xor(rq2, off, 64);
            rq3 += __shfl_xor(rq3, off, 64);
        }
        if (l15 == 0) {
            f32x4 out = (f32x4){rq0, rq1, rq2, rq3};
            *reinterpret_cast<f32x4*>(
                P + (size_t)(2 * tj + wc) * N + ti * 128 + wr * 64 + r * 16 + lhi * 4) = out;
        }
    }
    if (ti != tj) {
#pragma unroll
        for (int c = 0; c < 4; ++c) {
            float v = cs[c];
            v += __shfl_xor(v, 16, 64);
            v += __shfl_xor(v, 32, 64);
            if (lhi == 0)
                P[(size_t)(2 * ti + wr) * N + tj * 128 + wc * 64 + c * 16 + l15] = v;
        }
    }
}

// Kernel 3 (fused finale): per row, sum the 128 plane partials + diag term,
// log; block partial. Last block (device-scope counter) combines the 32
// partials with the 1024 pos partials -> loss.
__global__ void k_lse(const float* __restrict__ P, const float* __restrict__ diag,
                      const float* __restrict__ pos_partial, int n_pos,
                      float* __restrict__ part, unsigned int* __restrict__ counter,
                      float* __restrict__ out, int N) {
    __shared__ float red[4];
    const int lane = threadIdx.x & 63, wv = threadIdx.x >> 6;
    const int row = blockIdx.x * 256 + threadIdx.x;
    float s = diag[row];
#pragma unroll 8
    for (int k = 0; k < NPLANE; ++k) s += P[(size_t)k * N + row];
    float local = __logf(s);
#pragma unroll
    for (int off = 32; off >= 1; off >>= 1) local += __shfl_xor(local, off, 64);
    if (lane == 0) red[wv] = local;
    __syncthreads();
    bool last = false;
    if (threadIdx.x == 0) {
        part[blockIdx.x] = red[0] + red[1] + red[2] + red[3];
        __threadfence();
        last = (atomicAdd(counter, 1u) == LSE_BLOCKS - 1);
    }
    // broadcast "last" to the block
    __shared__ int lastflag;
    if (threadIdx.x == 0) lastflag = last ? 1 : 0;
    __syncthreads();
    if (lastflag) {
        __threadfence();   // acquire: other blocks' part[] writes visible
        float t = 0.f;
        for (int i = threadIdx.x; i < LSE_BLOCKS; i += 256) t += part[i];
        for (int i = threadIdx.x; i < n_pos; i += 256) t -= pos_partial[i];
#pragma unroll
        for (int off = 32; off >= 1; off >>= 1) t += __shfl_xor(t, off, 64);
        if (lane == 0) red[wv] = t;
        __syncthreads();
        if (threadIdx.x == 0)
            out[0] = (red[0] + red[1] + red[2] + red[3]) / (float)N;
    }
}

extern "C" void kernel_launch(void* const* d_in, const int* in_sizes, int n_in,
                              void* d_out, int out_size, void* d_ws, size_t ws_size,
                              hipStream_t stream) {
    const float* zi = (const float*)d_in[0];
    const float* zj = (const float*)d_in[1];
    const int B = in_sizes[0] / D;   // 4096
    const int N = 2 * B;             // 8192

    char* ws = (char*)d_ws;
    unsigned char* zn = (unsigned char*)ws;              // N*D fp8 = 2 MB
    float* diag = (float*)(ws + (size_t)N * D);          // N f32 = 32 KB
    float* pos_partial = diag + N;                       // B/4 = 1024 f32
    float* part = pos_partial + 1024;                    // 32 f32
    unsigned int* counter = (unsigned int*)(part + 32);  // 1 u32 (+pad)
    float* P = part + 64;                                // 128*N f32 = 4 MB

    float* out = (float*)d_out;

    const int npb = B / 4;  // 1024 k_norm blocks == pos partials
    hipLaunchKernelGGL(k_norm, dim3(npb), dim3(256), 0, stream, zi, zj, zn, diag,
                       pos_partial, counter, B);
    hipLaunchKernelGGL(k_main, dim3(NBLK), dim3(256), 0, stream, zn, P, N);
    hipLaunchKernelGGL(k_lse, dim3(LSE_BLOCKS), dim3(256), 0, stream, P, diag,
                       pos_partial, npb, part, counter, out, N);
}